// Round 6
// baseline (639.125 us; speedup 1.0000x reference)
//
#include <hip/hip_runtime.h>

#define NN 32768
#define EE 262144

static __device__ __forceinline__ float sigm(float x){
  return 1.0f / (1.0f + __expf(-x));
}

// ---------------- node pass: o3-layernorm + src/dst linears ----------------
__global__ __launch_bounds__(256) void k_node(
    const float* __restrict__ node,
    const float* __restrict__ Wss, const float* __restrict__ Wsv,
    const float* __restrict__ Wds, const float* __restrict__ Wdv,
    float* __restrict__ ss, float* __restrict__ ds,
    float* __restrict__ sv, float* __restrict__ dv)
{
  int n = blockIdx.x * 256 + threadIdx.x;
  if (n >= NN) return;
  const float4* row = reinterpret_cast<const float4*>(node + (size_t)n * 80);
  float s[32], v[48];
#pragma unroll
  for (int i = 0; i < 8; ++i){
    float4 t = row[i];
    s[i*4+0]=t.x; s[i*4+1]=t.y; s[i*4+2]=t.z; s[i*4+3]=t.w;
  }
#pragma unroll
  for (int i = 0; i < 12; ++i){
    float4 t = row[8+i];
    v[i*4+0]=t.x; v[i*4+1]=t.y; v[i*4+2]=t.z; v[i*4+3]=t.w;
  }
  float mean = 0.f;
#pragma unroll
  for (int i=0;i<32;++i) mean += s[i];
  mean *= (1.0f/32.0f);
  float var = 0.f;
#pragma unroll
  for (int i=0;i<32;++i){ float d0 = s[i]-mean; var += d0*d0; }
  var *= (1.0f/32.0f);
  float sinv = rsqrtf(var + 1e-5f);
#pragma unroll
  for (int i=0;i<32;++i) s[i] = (s[i]-mean)*sinv;
  float n2 = 0.f;
#pragma unroll
  for (int i=0;i<48;++i) n2 += v[i]*v[i];
  n2 *= (1.0f/16.0f);
  float vinv = rsqrtf(n2 + 1e-5f);
#pragma unroll
  for (int i=0;i<48;++i) v[i] *= vinv;

  float* ssr = ss + (size_t)n*32;
  float* dsr = ds + (size_t)n*32;
#pragma unroll 1
  for (int d=0; d<32; ++d){
    float a=0.f, b=0.f;
#pragma unroll
    for (int c=0;c<32;++c){ a += s[c]*Wss[c*32+d]; b += s[c]*Wds[c*32+d]; }
    ssr[d]=a; dsr[d]=b;
  }
  float* svr = sv + (size_t)n*48;
  float* dvr = dv + (size_t)n*48;
#pragma unroll 1
  for (int d=0; d<16; ++d){
#pragma unroll
    for (int x=0;x<3;++x){
      float a=0.f, b=0.f;
#pragma unroll
      for (int c=0;c<16;++c){ a += v[c*3+x]*Wsv[c*16+d]; b += v[c*3+x]*Wdv[c*16+d]; }
      svr[d*3+x]=a; dvr[d*3+x]=b;
    }
  }
}

// ---------------- CSR build ----------------
__global__ __launch_bounds__(256) void k_hist(const int* __restrict__ ei, int* __restrict__ deg){
  int e = blockIdx.x*256 + threadIdx.x;
  if (e >= EE) return;
  atomicAdd(deg + ei[EE + e], 1);
}

__global__ __launch_bounds__(1024) void k_scan(const int* __restrict__ deg,
                                               int* __restrict__ base, int* __restrict__ cursor){
  __shared__ int lds[1024];
  int t = threadIdx.x;
  int v[32];
#pragma unroll
  for (int i=0;i<32;++i) v[i] = deg[t*32+i];
  int run = 0;
#pragma unroll
  for (int i=0;i<32;++i){ int x=v[i]; v[i]=run; run+=x; }
  lds[t]=run; __syncthreads();
  for (int off=1; off<1024; off<<=1){
    int add = (t>=off) ? lds[t-off] : 0;
    __syncthreads();
    lds[t] += add;
    __syncthreads();
  }
  int pre = (t==0) ? 0 : lds[t-1];
#pragma unroll
  for (int i=0;i<32;++i){ int b = pre + v[i]; base[t*32+i]=b; cursor[t*32+i]=b; }
}

__global__ __launch_bounds__(256) void k_scatter(const int* __restrict__ ei,
                                                 int* __restrict__ cursor, int* __restrict__ csr,
                                                 int* __restrict__ dsts){
  int e = blockIdx.x*256 + threadIdx.x;
  if (e >= EE) return;
  int d = ei[EE + e];
  int pos = atomicAdd(cursor + d, 1);
  csr[pos] = e;
  dsts[pos] = d;
}

// ============== cooperative edge pass A: attention logits ==================
#define A_RBFA 0
#define A_RBFD 640
#define A_WA   960
#define A_ADOT 4288
#define A_EDG  4352
#define A_ESTR 152

__global__ __launch_bounds__(512) void k_edgeA2(
    const int* __restrict__ ei,
    const float* __restrict__ rbf, const float* __restrict__ rsh,
    const float* __restrict__ Wrbf, const float* __restrict__ Wa,
    const float* __restrict__ adot,
    const float* __restrict__ ss, const float* __restrict__ ds,
    const float* __restrict__ sv, const float* __restrict__ dv,
    float* __restrict__ logits)
{
  __shared__ __align__(16) float SH[A_EDG + 16*A_ESTR];
  const int t = threadIdx.x;
  for (int i=t; i<32*16; i+=512){ int row=i>>4, j=i&15; SH[A_RBFA+row*20+j] = Wrbf[j*112+row]; }
  for (int i=t; i<16*16; i+=512){ int row=i>>4, j=i&15; SH[A_RBFD+row*20+j] = Wrbf[j*112+80+row]; }
  for (int i=t; i<64*48; i+=512){ int o=i/48, k=i-48*o; SH[A_WA+o*52+k] = Wa[k*64+o]; }
  for (int i=t; i<64;    i+=512){ SH[A_ADOT+i] = adot[i]; }
  __syncthreads();

  const int g = t >> 5;
  const int c = t & 31;
  float* E = &SH[A_EDG + g*A_ESTR];
  const float IS3 = 0.57735026918962576f;

#pragma unroll 1
  for (int tile=0; tile<16; ++tile){
    const int e = blockIdx.x*256 + tile*16 + g;
    const int src = ei[e], dst = ei[EE + e];

    if (c < 8){
      float4 a = *reinterpret_cast<const float4*>(ss + (size_t)src*32 + c*4);
      float4 b = *reinterpret_cast<const float4*>(ds + (size_t)dst*32 + c*4);
      float4 o; o.x=a.x+b.x; o.y=a.y+b.y; o.z=a.z+b.z; o.w=a.w+b.w;
      *reinterpret_cast<float4*>(&E[c*4]) = o;
    } else if (c < 20){
      int i = c-8;
      float4 a = *reinterpret_cast<const float4*>(sv + (size_t)src*48 + i*4);
      float4 b = *reinterpret_cast<const float4*>(dv + (size_t)dst*48 + i*4);
      float4 o; o.x=a.x+b.x; o.y=a.y+b.y; o.z=a.z+b.z; o.w=a.w+b.w;
      *reinterpret_cast<float4*>(&E[32+i*4]) = o;
    } else if (c < 24){
      int i = c-20;
      *reinterpret_cast<float4*>(&E[80+i*4]) =
          *reinterpret_cast<const float4*>(rbf + (size_t)e*16 + i*4);
    } else if (c == 24){
      *reinterpret_cast<float4*>(&E[96]) =
          *reinterpret_cast<const float4*>(rsh + (size_t)e*4);
    }

    float rr[16];
#pragma unroll
    for (int i=0;i<4;++i) *reinterpret_cast<float4*>(&rr[i*4]) =
        *reinterpret_cast<const float4*>(&E[80+i*4]);
    const float y0=E[96], y1x=E[97], y1y=E[98], y1z=E[99];
    {
      float wA=0.f;
#pragma unroll
      for (int j4=0;j4<4;++j4){
        float4 a0 = *reinterpret_cast<const float4*>(&SH[A_RBFA + c*20 + j4*4]);
        wA += rr[j4*4+0]*a0.x + rr[j4*4+1]*a0.y + rr[j4*4+2]*a0.z + rr[j4*4+3]*a0.w;
      }
      E[104+c] = wA * E[c] * y0;
    }
    if (c < 16){
      float wD=0.f;
#pragma unroll
      for (int j4=0;j4<4;++j4){
        float4 a0 = *reinterpret_cast<const float4*>(&SH[A_RBFD + c*20 + j4*4]);
        wD += rr[j4*4+0]*a0.x + rr[j4*4+1]*a0.y + rr[j4*4+2]*a0.z + rr[j4*4+3]*a0.w;
      }
      float vx=E[32+c*3], vy=E[33+c*3], vz=E[34+c*3];
      E[136+c] = wD * (vx*y1x + vy*y1y + vz*y1z) * IS3;
    }

    float mm[48];
#pragma unroll
    for (int k4=0;k4<12;++k4) *reinterpret_cast<float4*>(&mm[k4*4]) =
        *reinterpret_cast<const float4*>(&E[104+k4*4]);
    float acc0=0.f, acc1=0.f;
#pragma unroll
    for (int k4=0;k4<12;++k4){
      float4 w0 = *reinterpret_cast<const float4*>(&SH[A_WA + c*52 + k4*4]);
      float4 w1 = *reinterpret_cast<const float4*>(&SH[A_WA + (32+c)*52 + k4*4]);
      acc0 += mm[k4*4+0]*w0.x + mm[k4*4+1]*w0.y + mm[k4*4+2]*w0.z + mm[k4*4+3]*w0.w;
      acc1 += mm[k4*4+0]*w1.x + mm[k4*4+1]*w1.y + mm[k4*4+2]*w1.z + mm[k4*4+3]*w1.w;
    }
    acc0 = ((acc0 > 0.f) ? acc0 : 0.2f*acc0) * SH[A_ADOT+c];
    acc1 = ((acc1 > 0.f) ? acc1 : 0.2f*acc1) * SH[A_ADOT+32+c];
#pragma unroll
    for (int msk=8; msk>=1; msk>>=1){
      acc0 += __shfl_xor(acc0, msk);
      acc1 += __shfl_xor(acc1, msk);
    }
    if ((c & 15) == 0){
      int h0 = c >> 4;
      logits[(size_t)e*4 + h0]     = acc0;
      logits[(size_t)e*4 + 2 + h0] = acc1;
    }
  }
}

// ------------- per-(dst,head) softmax stats via CSR (no atomics) ----------
__global__ __launch_bounds__(256) void k_soft(
    const int* __restrict__ base, const int* __restrict__ deg,
    const int* __restrict__ csr, const float* __restrict__ logits,
    float* __restrict__ m, float* __restrict__ iden)
{
  int id = blockIdx.x*256 + threadIdx.x;
  if (id >= NN*4) return;
  int d = id >> 2, h = id & 3;
  int b = base[d], n = deg[d];
  float mm = -3.4e38f;
  for (int i=0;i<n;++i){ int e = csr[b+i]; mm = fmaxf(mm, logits[(size_t)e*4+h]); }
  float s = 0.f;
  for (int i=0;i<n;++i){ int e = csr[b+i]; s += __expf(logits[(size_t)e*4+h] - mm); }
  m[id] = mm;
  iden[id] = (n>0) ? 1.0f/s : 0.f;
}

// ============ edge value pass, part A: through SiLU/gating ================
// Writes 88 floats/edge into wflat row (stride 96):
//   [0:32) vsg  [32:80) vvg(gated)  [80:84) alpha  [84:88) y
#define CA_RBF  0      // [112][20]
#define CA_VALS 2240   // [32][52]
#define CA_VVA  3904   // [16][36]
#define CA_VVB  4480   // [16][20]
#define CA_VVC  4800   // [16][20]
#define CA_G    5120   // [16][36]
#define CA_EDG  5696
#define CA_ESTR 400

__global__ __launch_bounds__(256) void k_edgeCa(
    const int* __restrict__ csr, const int* __restrict__ ei,
    const float* __restrict__ rbf, const float* __restrict__ rsh,
    const float* __restrict__ Wrbf,
    const float* __restrict__ Wvals, const float* __restrict__ Wvalv,
    const float* __restrict__ Wg,
    const float* __restrict__ ss, const float* __restrict__ ds,
    const float* __restrict__ sv, const float* __restrict__ dv,
    const float* __restrict__ logits, const float* __restrict__ m,
    const float* __restrict__ iden, float* __restrict__ wflat)
{
  __shared__ __align__(16) float SH[CA_EDG + 8*CA_ESTR];
  const int t = threadIdx.x;
  for (int i=t; i<112*16; i+=256){ int d=i>>4, k=i&15; SH[CA_RBF+d*20+k]  = Wrbf[k*112+d]; }
  for (int i=t; i<32*48;  i+=256){ int d=i/48, k=i-48*d; SH[CA_VALS+d*52+k] = Wvals[k*32+d]; }
  for (int i=t; i<16*32;  i+=256){ int d=i>>5, k=i&31; SH[CA_VVA+d*36+k]  = Wvalv[k*16+d]; }
  for (int i=t; i<16*16;  i+=256){ int d=i>>4, k=i&15; SH[CA_VVB+d*20+k]  = Wvalv[(32+k)*16+d]; }
  for (int i=t; i<16*16;  i+=256){ int d=i>>4, k=i&15; SH[CA_VVC+d*20+k]  = Wvalv[(48+k)*16+d]; }
  for (int i=t; i<16*32;  i+=256){ int d=i>>5, k=i&31; SH[CA_G+d*36+k]    = Wg[k*16+d]; }
  __syncthreads();

  const int g = t >> 5;
  const int c = t & 31;
  float* E = &SH[CA_EDG + g*CA_ESTR];
  const float IS3 = 0.57735026918962576f;
  const float IS2 = 0.70710678118654752f;

#pragma unroll 1
  for (int tile=0; tile<16; ++tile){
    const int pidx = blockIdx.x*128 + tile*8 + g;
    const int e = csr[pidx];
    const int src = ei[e], dst = ei[EE + e];

    if (c < 8){
      float4 a = *reinterpret_cast<const float4*>(ss + (size_t)src*32 + c*4);
      float4 b = *reinterpret_cast<const float4*>(ds + (size_t)dst*32 + c*4);
      float4 o; o.x=a.x+b.x; o.y=a.y+b.y; o.z=a.z+b.z; o.w=a.w+b.w;
      *reinterpret_cast<float4*>(&E[c*4]) = o;
    } else if (c < 20){
      int i = c-8;
      float4 a = *reinterpret_cast<const float4*>(sv + (size_t)src*48 + i*4);
      float4 b = *reinterpret_cast<const float4*>(dv + (size_t)dst*48 + i*4);
      float4 o; o.x=a.x+b.x; o.y=a.y+b.y; o.z=a.z+b.z; o.w=a.w+b.w;
      *reinterpret_cast<float4*>(&E[32+i*4]) = o;
    } else if (c < 24){
      int i = c-20;
      *reinterpret_cast<float4*>(&E[80+i*4]) =
          *reinterpret_cast<const float4*>(rbf + (size_t)e*16 + i*4);
    } else if (c == 24){
      *reinterpret_cast<float4*>(&E[96]) =
          *reinterpret_cast<const float4*>(rsh + (size_t)e*4);
    } else if (c == 25){
      float4 l4 = *reinterpret_cast<const float4*>(logits + (size_t)e*4);
      float4 m4 = *reinterpret_cast<const float4*>(m + (size_t)dst*4);
      float4 i4 = *reinterpret_cast<const float4*>(iden + (size_t)dst*4);
      E[100] = __expf(l4.x-m4.x)*i4.x;
      E[101] = __expf(l4.y-m4.y)*i4.y;
      E[102] = __expf(l4.z-m4.z)*i4.z;
      E[103] = __expf(l4.w-m4.w)*i4.w;
    }

    float rr[16];
#pragma unroll
    for (int i=0;i<4;++i) *reinterpret_cast<float4*>(&rr[i*4]) =
        *reinterpret_cast<const float4*>(&E[80+i*4]);
    float wA=0.f, wB=0.f, wC=0.f, wD=0.f;
#pragma unroll
    for (int j4=0;j4<4;++j4){
      float4 a0 = *reinterpret_cast<const float4*>(&SH[CA_RBF + c*20           + j4*4]);
      float4 a1 = *reinterpret_cast<const float4*>(&SH[CA_RBF + (32+c)*20      + j4*4]);
      float4 a2 = *reinterpret_cast<const float4*>(&SH[CA_RBF + (64+c)*20      + j4*4]);
      float4 a3 = *reinterpret_cast<const float4*>(&SH[CA_RBF + (96+(c&15))*20 + j4*4]);
      float r0=rr[j4*4+0], r1=rr[j4*4+1], r2=rr[j4*4+2], r3=rr[j4*4+3];
      wA += r0*a0.x + r1*a0.y + r2*a0.z + r3*a0.w;
      wB += r0*a1.x + r1*a1.y + r2*a1.z + r3*a1.w;
      wC += r0*a2.x + r1*a2.y + r2*a2.z + r3*a2.w;
      wD += r0*a3.x + r1*a3.y + r2*a3.z + r3*a3.w;
    }

    const float y0=E[96], y1x=E[97], y1y=E[98], y1z=E[99];
    const float s_c = E[c];
    E[104+c] = wA * s_c * y0;
    E[152+c] = wB * s_c;
    if (c >= 16){
      int k = c-16;
      float vx=E[32+k*3], vy=E[33+k*3], vz=E[34+k*3];
      E[136+k] = wC * (vx*y1x+vy*y1y+vz*y1z) * IS3;
    }
    if (c < 16){
      int k = c;
      float vx=E[32+k*3], vy=E[33+k*3], vz=E[34+k*3];
      float u = wC * y0;
      E[200+k]    = u*vx; E[216+k] = u*vy; E[232+k] = u*vz;
      float cx=(vy*y1z - vz*y1y)*IS2;
      float cy=(vz*y1x - vx*y1z)*IS2;
      float cz=(vx*y1y - vy*y1x)*IS2;
      E[248+k]    = wD*cx; E[264+k] = wD*cy; E[280+k] = wD*cz;
    }

    if (c < 16){
      float acc=0.f, accB=0.f;
#pragma unroll
      for (int k4=0;k4<8;k4+=2){
        float4 w0 = *reinterpret_cast<const float4*>(&SH[CA_VVA + c*36 + k4*4]);
        float4 t0 = *reinterpret_cast<const float4*>(&E[152+k4*4]);
        float4 w1 = *reinterpret_cast<const float4*>(&SH[CA_VVA + c*36 + k4*4+4]);
        float4 t1 = *reinterpret_cast<const float4*>(&E[152+k4*4+4]);
        acc  += w0.x*t0.x + w0.y*t0.y + w0.z*t0.z + w0.w*t0.w;
        accB += w1.x*t1.x + w1.y*t1.y + w1.z*t1.z + w1.w*t1.w;
      }
      E[184+c]=acc+accB;
    }

    {
      int d0=c/3, x0=c-3*d0;
      float acc0 = E[184+d0]*E[97+x0];
#pragma unroll
      for (int k4=0;k4<4;++k4){
        float4 wb = *reinterpret_cast<const float4*>(&SH[CA_VVB + d0*20 + k4*4]);
        float4 wc = *reinterpret_cast<const float4*>(&SH[CA_VVC + d0*20 + k4*4]);
        float4 pp = *reinterpret_cast<const float4*>(&E[200 + x0*16 + k4*4]);
        float4 qq = *reinterpret_cast<const float4*>(&E[248 + x0*16 + k4*4]);
        acc0 += pp.x*wb.x+pp.y*wb.y+pp.z*wb.z+pp.w*wb.w
              + qq.x*wc.x+qq.y*wc.y+qq.z*wc.z+qq.w*wc.w;
      }
      E[344+c]=acc0;
      if (c < 16){
        int l=32+c, d1=l/3, x1=l-3*d1;
        float acc1 = E[184+d1]*E[97+x1];
#pragma unroll
        for (int k4=0;k4<4;++k4){
          float4 wb = *reinterpret_cast<const float4*>(&SH[CA_VVB + d1*20 + k4*4]);
          float4 wc = *reinterpret_cast<const float4*>(&SH[CA_VVC + d1*20 + k4*4]);
          float4 pp = *reinterpret_cast<const float4*>(&E[200 + x1*16 + k4*4]);
          float4 qq = *reinterpret_cast<const float4*>(&E[248 + x1*16 + k4*4]);
          acc1 += pp.x*wb.x+pp.y*wb.y+pp.z*wb.z+pp.w*wb.w
                + qq.x*wc.x+qq.y*wc.y+qq.z*wc.z+qq.w*wc.w;
        }
        E[344+l]=acc1;
      }
    }

    float accv=0.f, accw=0.f;
#pragma unroll
    for (int k4=0;k4<12;k4+=2){
      float4 w0 = *reinterpret_cast<const float4*>(&SH[CA_VALS + c*52 + k4*4]);
      float4 m0 = *reinterpret_cast<const float4*>(&E[104+k4*4]);
      float4 w1 = *reinterpret_cast<const float4*>(&SH[CA_VALS + c*52 + k4*4+4]);
      float4 m1 = *reinterpret_cast<const float4*>(&E[104+k4*4+4]);
      accv += w0.x*m0.x + w0.y*m0.y + w0.z*m0.z + w0.w*m0.w;
      accw += w1.x*m1.x + w1.y*m1.y + w1.z*m1.z + w1.w*m1.w;
    }
    accv += accw;
    E[296+c]=accv;

    if (c < 16){
      float acc=0.f;
#pragma unroll
      for (int k4=0;k4<8;++k4){
        float4 ww = *reinterpret_cast<const float4*>(&SH[CA_G + c*36 + k4*4]);
        float4 vv4 = *reinterpret_cast<const float4*>(&E[296+k4*4]);
        acc += ww.x*vv4.x + ww.y*vv4.y + ww.z*vv4.z + ww.w*vv4.w;
      }
      E[328+c]=sigm(acc);
    }

    float* erow = wflat + (size_t)pidx*96;
    erow[c] = accv * sigm(accv);
    erow[32+c] = E[344+c]*E[328+c/3];
    if (c < 16){
      int l = 32+c;
      erow[64+c] = E[344+l]*E[328+l/3];
    }
    if (c < 8){
      erow[80+c] = (c<4) ? E[100+c] : E[96+c-4];
    }
  }
}

// ===== edge value pass, part B: second CG + projections + fused gather =====
// Each 32-lane group owns 16 CONSECUTIVE csr positions (sorted by dst).
// Lane c accumulates its 5 output channels across same-dst runs in registers
// and flushes via atomicAdd on dst change / window end.
#define CB_VLS  0      // [64][52]
#define CB_VLVA 3328   // [32][36]
#define CB_VLVB 4480   // [32][20]
#define CB_VLVC 5120   // [32][20]
#define CB_W2   5760   // [112]
#define CB_EDG  5872
#define CB_ESTR 240
// E: 0:vvg[48] 48:a[4] 52:y[4] 56:vs2[48] 104:t2[32]
//    136:p2x[16] 152:p2y 168:p2z 184:q2x 200:q2y 216:q2z

__global__ __launch_bounds__(256) void k_edgeCb(
    const int* __restrict__ dsts,
    const float* __restrict__ Wvls, const float* __restrict__ Wvlv,
    const float* __restrict__ w2, const float* __restrict__ wflat,
    float* __restrict__ agg)
{
  __shared__ __align__(16) float SH[CB_EDG + 8*CB_ESTR];
  const int t = threadIdx.x;
  for (int i=t; i<64*48; i+=256){ int d=i/48, k=i-48*d; SH[CB_VLS+d*52+k] = Wvls[k*64+d]; }
  for (int i=t; i<32*32; i+=256){ int d=i>>5, k=i&31; SH[CB_VLVA+d*36+k] = Wvlv[k*32+d]; }
  for (int i=t; i<32*16; i+=256){ int d=i>>4, k=i&15; SH[CB_VLVB+d*20+k] = Wvlv[(32+k)*32+d]; }
  for (int i=t; i<32*16; i+=256){ int d=i>>4, k=i&15; SH[CB_VLVC+d*20+k] = Wvlv[(48+k)*32+d]; }
  for (int i=t; i<112;   i+=256){ SH[CB_W2+i] = w2[i]; }
  __syncthreads();

  const int g = t >> 5;
  const int c = t & 31;
  float* E = &SH[CB_EDG + g*CB_ESTR];
  const float IS3 = 0.57735026918962576f;
  const float IS2 = 0.70710678118654752f;

  const int p0 = blockIdx.x*128 + g*16;
  int cur = dsts[p0];
  float ac0=0.f, ac1=0.f, ac2=0.f, ac3=0.f, ac4=0.f;

#pragma unroll 1
  for (int tile=0; tile<16; ++tile){
    const int pidx = p0 + tile;
    const int dst = dsts[pidx];
    if (dst != cur){
      float* ar = agg + (size_t)cur*160;
      atomicAdd(ar+c,       ac0);
      atomicAdd(ar+32+c,    ac1);
      atomicAdd(ar+64+c*3,  ac2);
      atomicAdd(ar+65+c*3,  ac3);
      atomicAdd(ar+66+c*3,  ac4);
      ac0=ac1=ac2=ac3=ac4=0.f;
      cur = dst;
    }
    const float* wrow = wflat + (size_t)pidx*96;

    const float vsc = wrow[c];
    E[c] = wrow[32+c];
    if (c < 16) E[32+c] = wrow[64+c];
    if (c < 8)  E[48+c] = wrow[80+c];

    const float y0=E[52], y1x=E[53], y1y=E[54], y1z=E[55];

    E[104+c] = SH[CB_W2+32+c]*vsc;
    E[56+c]  = SH[CB_W2+c]*vsc*y0;
    if (c >= 16){
      int k = c-16;
      float gx=E[k*3], gy=E[k*3+1], gz=E[k*3+2];
      E[88+k] = SH[CB_W2+80+k]*(gx*y1x+gy*y1y+gz*y1z)*IS3;
    }
    if (c < 16){
      int k = c;
      float gx=E[k*3], gy=E[k*3+1], gz=E[k*3+2];
      float u = SH[CB_W2+64+k]*y0;
      E[136+k]=u*gx; E[152+k]=u*gy; E[168+k]=u*gz;
      float cx=(gy*y1z - gz*y1y)*IS2;
      float cy=(gz*y1x - gx*y1z)*IS2;
      float cz=(gx*y1y - gy*y1x)*IS2;
      float wq = SH[CB_W2+96+k];
      E[184+k]=wq*cx; E[200+k]=wq*cy; E[216+k]=wq*cz;
    }

    const float a0=E[48], a1=E[49], a2h=E[50], a3h=E[51];

    {
      float f0a=0.f, f0b=0.f, f1a=0.f, f1b=0.f;
#pragma unroll
      for (int k4=0;k4<12;k4+=2){
        float4 v0 = *reinterpret_cast<const float4*>(&E[56+k4*4]);
        float4 v1 = *reinterpret_cast<const float4*>(&E[56+k4*4+4]);
        float4 wa0 = *reinterpret_cast<const float4*>(&SH[CB_VLS + c*52 + k4*4]);
        float4 wa1 = *reinterpret_cast<const float4*>(&SH[CB_VLS + c*52 + k4*4+4]);
        float4 wb0 = *reinterpret_cast<const float4*>(&SH[CB_VLS + (32+c)*52 + k4*4]);
        float4 wb1 = *reinterpret_cast<const float4*>(&SH[CB_VLS + (32+c)*52 + k4*4+4]);
        f0a += v0.x*wa0.x + v0.y*wa0.y + v0.z*wa0.z + v0.w*wa0.w;
        f0b += v1.x*wa1.x + v1.y*wa1.y + v1.z*wa1.z + v1.w*wa1.w;
        f1a += v0.x*wb0.x + v0.y*wb0.y + v0.z*wb0.z + v0.w*wb0.w;
        f1b += v1.x*wb1.x + v1.y*wb1.y + v1.z*wb1.z + v1.w*wb1.w;
      }
      ac0 += (f0a+f0b)*a0;
      ac1 += (f1a+f1b)*((c<8)?a0:a1);
    }

    {
      float A2=0.f, A2b=0.f;
#pragma unroll
      for (int k4=0;k4<8;k4+=2){
        float4 w0 = *reinterpret_cast<const float4*>(&SH[CB_VLVA + c*36 + k4*4]);
        float4 t0 = *reinterpret_cast<const float4*>(&E[104+k4*4]);
        float4 w1 = *reinterpret_cast<const float4*>(&SH[CB_VLVA + c*36 + k4*4+4]);
        float4 t1 = *reinterpret_cast<const float4*>(&E[104+k4*4+4]);
        A2  += w0.x*t0.x + w0.y*t0.y + w0.z*t0.z + w0.w*t0.w;
        A2b += w1.x*t1.x + w1.y*t1.y + w1.z*t1.z + w1.w*t1.w;
      }
      A2 += A2b;
      float b0=A2*y1x, b1=A2*y1y, b2=A2*y1z;
#pragma unroll
      for (int k4=0;k4<4;++k4){
        float4 wb = *reinterpret_cast<const float4*>(&SH[CB_VLVB + c*20 + k4*4]);
        float4 wc = *reinterpret_cast<const float4*>(&SH[CB_VLVC + c*20 + k4*4]);
        float4 pp0 = *reinterpret_cast<const float4*>(&E[136 + k4*4]);
        float4 pp1 = *reinterpret_cast<const float4*>(&E[152 + k4*4]);
        float4 pp2 = *reinterpret_cast<const float4*>(&E[168 + k4*4]);
        float4 qq0 = *reinterpret_cast<const float4*>(&E[184 + k4*4]);
        float4 qq1 = *reinterpret_cast<const float4*>(&E[200 + k4*4]);
        float4 qq2 = *reinterpret_cast<const float4*>(&E[216 + k4*4]);
        b0 += pp0.x*wb.x+pp0.y*wb.y+pp0.z*wb.z+pp0.w*wb.w + qq0.x*wc.x+qq0.y*wc.y+qq0.z*wc.z+qq0.w*wc.w;
        b1 += pp1.x*wb.x+pp1.y*wb.y+pp1.z*wb.z+pp1.w*wb.w + qq1.x*wc.x+qq1.y*wc.y+qq1.z*wc.z+qq1.w*wc.w;
        b2 += pp2.x*wb.x+pp2.y*wb.y+pp2.z*wb.z+pp2.w*wb.w + qq2.x*wc.x+qq2.y*wc.y+qq2.z*wc.z+qq2.w*wc.w;
      }
      int o = 64 + c*3;
      float aw0 = (o   < 80) ? a1 : ((o   < 120) ? a2h : a3h);
      float aw1 = (o+1 < 80) ? a1 : ((o+1 < 120) ? a2h : a3h);
      float aw2 = (o+2 < 80) ? a1 : ((o+2 < 120) ? a2h : a3h);
      ac2 += b0*aw0;
      ac3 += b1*aw1;
      ac4 += b2*aw2;
    }
  }

  // final flush
  {
    float* ar = agg + (size_t)cur*160;
    atomicAdd(ar+c,       ac0);
    atomicAdd(ar+32+c,    ac1);
    atomicAdd(ar+64+c*3,  ac2);
    atomicAdd(ar+65+c*3,  ac3);
    atomicAdd(ar+66+c*3,  ac4);
  }
}

// ------------- output pass: Wp projections + residual ----------------------
__global__ __launch_bounds__(256) void k_out(
    const float* __restrict__ node, const float* __restrict__ agg,
    const float* __restrict__ Wps, const float* __restrict__ Wpv,
    float* __restrict__ out)
{
  int n = blockIdx.x * 256 + threadIdx.x;
  if (n >= NN) return;
  const float* ar = agg + (size_t)n*160;
  const float* nr = node + (size_t)n*80;
  float* orow = out + (size_t)n*80;

  float a[64];
  { const float4* ap = reinterpret_cast<const float4*>(ar);
#pragma unroll
    for (int i=0;i<16;++i){ float4 t=ap[i];
      a[i*4]=t.x; a[i*4+1]=t.y; a[i*4+2]=t.z; a[i*4+3]=t.w; } }
#pragma unroll 1
  for (int d=0; d<32; ++d){
    float acc=0.f;
#pragma unroll
    for (int c=0;c<64;++c) acc += a[c]*Wps[c*32+d];
    orow[d] = nr[d] + acc;
  }
  float b[96];
  { const float4* bp = reinterpret_cast<const float4*>(ar + 64);
#pragma unroll
    for (int i=0;i<24;++i){ float4 t=bp[i];
      b[i*4]=t.x; b[i*4+1]=t.y; b[i*4+2]=t.z; b[i*4+3]=t.w; } }
#pragma unroll 1
  for (int d=0; d<16; ++d){
#pragma unroll
    for (int x=0;x<3;++x){
      float acc=0.f;
#pragma unroll
      for (int c=0;c<32;++c) acc += b[c*3+x]*Wpv[c*16+d];
      orow[32+d*3+x] = nr[32+d*3+x] + acc;
    }
  }
}

extern "C" void kernel_launch(void* const* d_in, const int* in_sizes, int n_in,
                              void* d_out, int out_size, void* d_ws, size_t ws_size,
                              hipStream_t stream)
{
  const float* node   = (const float*)d_in[0];
  const float* rbf    = (const float*)d_in[1];
  const float* rsh    = (const float*)d_in[2];
  const float* Wsrc_s = (const float*)d_in[3];
  const float* Wsrc_v = (const float*)d_in[4];
  const float* Wdst_s = (const float*)d_in[5];
  const float* Wdst_v = (const float*)d_in[6];
  const float* W_rbf  = (const float*)d_in[7];
  const float* dtp2   = (const float*)d_in[8];
  const float* Wa     = (const float*)d_in[9];
  const float* adot   = (const float*)d_in[10];
  const float* Wval_s = (const float*)d_in[11];
  const float* Wval_v = (const float*)d_in[12];
  const float* Wg     = (const float*)d_in[13];
  const float* Wvl_s  = (const float*)d_in[14];
  const float* Wvl_v  = (const float*)d_in[15];
  const float* Wp_s   = (const float*)d_in[16];
  const float* Wp_v   = (const float*)d_in[17];
  const int*   ei     = (const int*)d_in[18];

  float* ws = (float*)d_ws;

  size_t off = 0;
  float* ss   = ws + off; off += (size_t)NN*32;
  float* ds   = ws + off; off += (size_t)NN*32;
  float* sv   = ws + off; off += (size_t)NN*48;
  float* dv   = ws + off; off += (size_t)NN*48;
  float* lg   = ws + off; off += (size_t)EE*4;
  float* m    = ws + off; off += (size_t)NN*4;
  float* iden = ws + off; off += (size_t)NN*4;
  int* deg    = (int*)(ws + off); off += (size_t)NN;
  int* base   = (int*)(ws + off); off += (size_t)NN;
  int* cursor = (int*)(ws + off); off += (size_t)NN;
  int* csr    = (int*)(ws + off); off += (size_t)EE;
  int* dsts   = (int*)(ws + off); off += (size_t)EE;
  float* agg  = ws + off; off += (size_t)NN*160;
  float* wflat= ws + off; off += (size_t)EE*96;
  size_t need_new = off * sizeof(float);
  if (ws_size < need_new) return;

  hipMemsetAsync(deg, 0, (size_t)NN*sizeof(int), stream);
  hipMemsetAsync(agg, 0, (size_t)NN*160*sizeof(float), stream);
  k_node   <<<NN/256, 256, 0, stream>>>(node, Wsrc_s, Wsrc_v, Wdst_s, Wdst_v, ss, ds, sv, dv);
  k_hist   <<<EE/256, 256, 0, stream>>>(ei, deg);
  k_scan   <<<1, 1024, 0, stream>>>(deg, base, cursor);
  k_scatter<<<EE/256, 256, 0, stream>>>(ei, cursor, csr, dsts);
  k_edgeA2 <<<EE/256, 512, 0, stream>>>(ei, rbf, rsh, W_rbf, Wa, adot, ss, ds, sv, dv, lg);
  k_soft   <<<(NN*4)/256, 256, 0, stream>>>(base, deg, csr, lg, m, iden);
  k_edgeCa <<<EE/128, 256, 0, stream>>>(csr, ei, rbf, rsh, W_rbf, Wval_s, Wval_v, Wg,
                                        ss, ds, sv, dv, lg, m, iden, wflat);
  k_edgeCb <<<EE/128, 256, 0, stream>>>(dsts, Wvl_s, Wvl_v, dtp2, wflat, agg);
  k_out    <<<NN/256, 256, 0, stream>>>(node, agg, Wp_s, Wp_v, (float*)d_out);
}